// Round 1
// baseline (1467.458 us; speedup 1.0000x reference)
//
#include <hip/hip_runtime.h>
#include <math.h>

#define N_NODES 100000
#define N_EDGES 1600000
#define D 64

// ---------------------------------------------------------------------------
// K1: h = feat @ kern  (fp32 vector GEMM, K=64, D_OUT=64)
//     also writes out_base = h*skip + bias into d_out
// block = 256 threads -> 16 rows x 64 cols, 4 cols/thread
// ---------------------------------------------------------------------------
__global__ __launch_bounds__(256) void gemm_kernel(
    const float* __restrict__ feat, const float* __restrict__ kern,
    const float* __restrict__ bias, const float* __restrict__ skip,
    float* __restrict__ h, float* __restrict__ out)
{
    __shared__ float ks[64 * 64];   // kernel tile, row-major [k][c]
    __shared__ float fs[16 * 64];   // 16 feature rows

    const int t = threadIdx.x;
    const int row0 = blockIdx.x * 16;

    // load kernel: 4096 floats = 1024 float4, 256 threads -> 4 each
    {
        const float4* k4 = (const float4*)kern;
        float4* ks4 = (float4*)ks;
        #pragma unroll
        for (int i = 0; i < 4; i++) ks4[t + 256 * i] = k4[t + 256 * i];
    }
    // load 16 feature rows: 1024 floats = 256 float4
    {
        const float4* f4 = (const float4*)(feat + (size_t)row0 * D);
        ((float4*)fs)[t] = f4[t];
    }
    __syncthreads();

    const int r  = t >> 4;   // 0..15 row within tile
    const int cg = t & 15;   // col group (4 cols)

    float4 acc = make_float4(0.f, 0.f, 0.f, 0.f);
    #pragma unroll
    for (int k4 = 0; k4 < 16; k4++) {
        float4 f  = ((const float4*)(fs + r * D))[k4];
        float4 k0 = ((const float4*)(ks + (4 * k4 + 0) * D))[cg];
        float4 k1 = ((const float4*)(ks + (4 * k4 + 1) * D))[cg];
        float4 k2 = ((const float4*)(ks + (4 * k4 + 2) * D))[cg];
        float4 k3 = ((const float4*)(ks + (4 * k4 + 3) * D))[cg];
        acc.x += f.x * k0.x + f.y * k1.x + f.z * k2.x + f.w * k3.x;
        acc.y += f.x * k0.y + f.y * k1.y + f.z * k2.y + f.w * k3.y;
        acc.z += f.x * k0.z + f.y * k1.z + f.z * k2.z + f.w * k3.z;
        acc.w += f.x * k0.w + f.y * k1.w + f.z * k2.w + f.w * k3.w;
    }

    const int row = row0 + r;
    ((float4*)(h + (size_t)row * D))[cg] = acc;

    float4 sk = ((const float4*)skip)[cg];
    float4 bi = ((const float4*)bias)[cg];
    float4 ob = make_float4(acc.x * sk.x + bi.x, acc.y * sk.y + bi.y,
                            acc.z * sk.z + bi.z, acc.w * sk.w + bi.w);
    ((float4*)(out + (size_t)row * D))[cg] = ob;
}

// ---------------------------------------------------------------------------
// K2: SpMM scatter: out[row] += val * h[col]
// 16 lanes per edge, 4 dims per lane (float4 gather), scalar fp32 atomics
// ---------------------------------------------------------------------------
__global__ __launch_bounds__(256) void spmm_kernel(
    const int* __restrict__ erow, const int* __restrict__ ecol,
    const float* __restrict__ eval, const float* __restrict__ h,
    float* __restrict__ out)
{
    const int gid  = blockIdx.x * 256 + threadIdx.x;
    const int e    = gid >> 4;
    const int lane = gid & 15;
    if (e >= N_EDGES) return;

    const int row = erow[e];
    const int col = ecol[e];
    const float v = eval[e];

    float4 hv = ((const float4*)(h + (size_t)col * D))[lane];
    float* dst = out + (size_t)row * D + lane * 4;
    atomicAdd(dst + 0, v * hv.x);
    atomicAdd(dst + 1, v * hv.y);
    atomicAdd(dst + 2, v * hv.z);
    atomicAdd(dst + 3, v * hv.w);
}

// ---------------------------------------------------------------------------
// K3: in-place SELU over d_out
// ---------------------------------------------------------------------------
__global__ __launch_bounds__(256) void selu_kernel(float* __restrict__ out)
{
    const float scale = 1.0507009873554805f;
    const float alpha = 1.6732632423543772f;
    const int i = blockIdx.x * 256 + threadIdx.x;  // one float4 per thread
    float4* p = ((float4*)out) + i;
    float4 x = *p;
    x.x = x.x > 0.f ? scale * x.x : scale * alpha * (expf(x.x) - 1.f);
    x.y = x.y > 0.f ? scale * x.y : scale * alpha * (expf(x.y) - 1.f);
    x.z = x.z > 0.f ? scale * x.z : scale * alpha * (expf(x.z) - 1.f);
    x.w = x.w > 0.f ? scale * x.w : scale * alpha * (expf(x.w) - 1.f);
    *p = x;
}

extern "C" void kernel_launch(void* const* d_in, const int* in_sizes, int n_in,
                              void* d_out, int out_size, void* d_ws, size_t ws_size,
                              hipStream_t stream)
{
    const float* feat = (const float*)d_in[0];
    const float* kern = (const float*)d_in[1];
    const float* bias = (const float*)d_in[2];
    const float* skip = (const float*)d_in[3];
    const int*   erow = (const int*)d_in[4];
    const int*   ecol = (const int*)d_in[5];
    const float* eval = (const float*)d_in[6];
    float* out = (float*)d_out;
    float* h   = (float*)d_ws;   // 100000*64*4 = 25.6 MB scratch

    // K1: projection + skip/bias base   (100000/16 = 6250 blocks exactly)
    hipLaunchKernelGGL(gemm_kernel, dim3(N_NODES / 16), dim3(256), 0, stream,
                       feat, kern, bias, skip, h, out);
    // K2: edge scatter  (1.6M edges * 16 threads / 256 = 100000 blocks)
    hipLaunchKernelGGL(spmm_kernel, dim3(N_EDGES * 16 / 256), dim3(256), 0, stream,
                       erow, ecol, eval, h, out);
    // K3: SELU  (6.4M floats / 4 / 256 = 6250 blocks)
    hipLaunchKernelGGL(selu_kernel, dim3(N_NODES * D / 4 / 256), dim3(256), 0, stream,
                       out);
}

// Round 2
// 378.336 us; speedup vs baseline: 3.8787x; 3.8787x over previous
//
#include <hip/hip_runtime.h>
#include <math.h>

#define N_NODES 100000
#define N_EDGES 1600000
#define D 64
#define NB 391          // ceil(N_NODES/256)

typedef unsigned int u32;

// ---------------------------------------------------------------------------
// K1: h = feat @ kern  (fp32 vector GEMM, K=64, D_OUT=64)
// block = 256 threads -> 16 rows x 64 cols, 4 cols/thread
// ---------------------------------------------------------------------------
__global__ __launch_bounds__(256) void gemm_kernel(
    const float* __restrict__ feat, const float* __restrict__ kern,
    float* __restrict__ h)
{
    __shared__ float ks[64 * 64];   // kernel tile, row-major [k][c]
    __shared__ float fs[16 * 64];   // 16 feature rows

    const int t = threadIdx.x;
    const int row0 = blockIdx.x * 16;

    {
        const float4* k4 = (const float4*)kern;
        float4* ks4 = (float4*)ks;
        #pragma unroll
        for (int i = 0; i < 4; i++) ks4[t + 256 * i] = k4[t + 256 * i];
    }
    {
        const float4* f4 = (const float4*)(feat + (size_t)row0 * D);
        ((float4*)fs)[t] = f4[t];
    }
    __syncthreads();

    const int r  = t >> 4;
    const int cg = t & 15;

    float4 acc = make_float4(0.f, 0.f, 0.f, 0.f);
    #pragma unroll
    for (int k4 = 0; k4 < 16; k4++) {
        float4 f  = ((const float4*)(fs + r * D))[k4];
        float4 k0 = ((const float4*)(ks + (4 * k4 + 0) * D))[cg];
        float4 k1 = ((const float4*)(ks + (4 * k4 + 1) * D))[cg];
        float4 k2 = ((const float4*)(ks + (4 * k4 + 2) * D))[cg];
        float4 k3 = ((const float4*)(ks + (4 * k4 + 3) * D))[cg];
        acc.x += f.x * k0.x + f.y * k1.x + f.z * k2.x + f.w * k3.x;
        acc.y += f.x * k0.y + f.y * k1.y + f.z * k2.y + f.w * k3.y;
        acc.z += f.x * k0.z + f.y * k1.z + f.z * k2.z + f.w * k3.z;
        acc.w += f.x * k0.w + f.y * k1.w + f.z * k2.w + f.w * k3.w;
    }
    ((float4*)(h + (size_t)(row0 + r) * D))[cg] = acc;
}

// ---------------------------------------------------------------------------
// CSR build: zero counts -> histogram -> 3-kernel exclusive scan -> scatter
// ---------------------------------------------------------------------------
__global__ void zero_cnt(u32* __restrict__ cnt)
{
    int i = blockIdx.x * 256 + threadIdx.x;
    if (i < N_NODES) cnt[i] = 0u;
}

__global__ void hist_kernel(const int* __restrict__ erow, u32* __restrict__ cnt)
{
    int i = blockIdx.x * 256 + threadIdx.x;   // exactly N_EDGES threads
    atomicAdd(&cnt[erow[i]], 1u);
}

__global__ void block_sums(const u32* __restrict__ cnt, u32* __restrict__ bsum)
{
    __shared__ u32 s[256];
    int t = threadIdx.x;
    int i = blockIdx.x * 256 + t;
    s[t] = (i < N_NODES) ? cnt[i] : 0u;
    __syncthreads();
    for (int d = 128; d > 0; d >>= 1) {
        if (t < d) s[t] += s[t + d];
        __syncthreads();
    }
    if (t == 0) bsum[blockIdx.x] = s[0];
}

__global__ void scan_bsums(const u32* __restrict__ bsum, u32* __restrict__ bbase)
{
    __shared__ u32 s[512];
    int t = threadIdx.x;
    u32 v = (t < NB) ? bsum[t] : 0u;
    s[t] = v;
    __syncthreads();
    for (int d = 1; d < 512; d <<= 1) {
        u32 a = (t >= d) ? s[t - d] : 0u;
        __syncthreads();
        s[t] += a;
        __syncthreads();
    }
    if (t < NB) bbase[t] = s[t] - v;   // exclusive
}

__global__ void scan_final(const u32* __restrict__ cnt, const u32* __restrict__ bbase,
                           u32* __restrict__ off, u32* __restrict__ cur)
{
    __shared__ u32 s[256];
    int t = threadIdx.x;
    int i = blockIdx.x * 256 + t;
    u32 v = (i < N_NODES) ? cnt[i] : 0u;
    s[t] = v;
    __syncthreads();
    for (int d = 1; d < 256; d <<= 1) {
        u32 a = (t >= d) ? s[t - d] : 0u;
        __syncthreads();
        s[t] += a;
        __syncthreads();
    }
    if (i < N_NODES) {
        u32 o = bbase[blockIdx.x] + s[t] - v;
        off[i] = o;
        cur[i] = o;
    }
}

__global__ void scatter_kernel(const int* __restrict__ erow, const int* __restrict__ ecol,
                               const float* __restrict__ eval, u32* __restrict__ cur,
                               int* __restrict__ scol, float* __restrict__ sval)
{
    int i = blockIdx.x * 256 + threadIdx.x;   // exactly N_EDGES threads
    int r = erow[i];
    u32 p = atomicAdd(&cur[r], 1u);
    scol[p] = ecol[i];
    sval[p] = eval[i];
}

// ---------------------------------------------------------------------------
// Aggregation: one wave per row, lane = output dim.
// out[row] = selu(h[row]*skip + bias + sum_e val_e * h[col_e])
// ---------------------------------------------------------------------------
__global__ __launch_bounds__(256) void agg_kernel(
    const u32* __restrict__ off, const u32* __restrict__ cnt,
    const int* __restrict__ scol, const float* __restrict__ sval,
    const float* __restrict__ h, const float* __restrict__ skip,
    const float* __restrict__ bias, float* __restrict__ out)
{
    const int row  = blockIdx.x * 4 + (threadIdx.x >> 6);   // exactly N_NODES waves
    const int lane = threadIdx.x & 63;

    u32 j   = off[row];
    u32 end = j + cnt[row];
    float acc = 0.f;

    for (; j + 4 <= end; j += 4) {
        int   c0 = scol[j],     c1 = scol[j + 1], c2 = scol[j + 2], c3 = scol[j + 3];
        float v0 = sval[j],     v1 = sval[j + 1], v2 = sval[j + 2], v3 = sval[j + 3];
        float h0 = h[(size_t)c0 * D + lane];
        float h1 = h[(size_t)c1 * D + lane];
        float h2 = h[(size_t)c2 * D + lane];
        float h3 = h[(size_t)c3 * D + lane];
        acc += v0 * h0;
        acc += v1 * h1;
        acc += v2 * h2;
        acc += v3 * h3;
    }
    for (; j < end; ++j)
        acc += sval[j] * h[(size_t)scol[j] * D + lane];

    float x = h[(size_t)row * D + lane] * skip[lane] + bias[lane] + acc;
    const float scale = 1.0507009873554805f;
    const float alpha = 1.6732632423543772f;
    out[(size_t)row * D + lane] = x > 0.f ? scale * x
                                          : scale * alpha * (expf(x) - 1.f);
}

extern "C" void kernel_launch(void* const* d_in, const int* in_sizes, int n_in,
                              void* d_out, int out_size, void* d_ws, size_t ws_size,
                              hipStream_t stream)
{
    const float* feat = (const float*)d_in[0];
    const float* kern = (const float*)d_in[1];
    const float* bias = (const float*)d_in[2];
    const float* skip = (const float*)d_in[3];
    const int*   erow = (const int*)d_in[4];
    const int*   ecol = (const int*)d_in[5];
    const float* eval = (const float*)d_in[6];
    float* out = (float*)d_out;

    // workspace layout (floats/u32s are both 4 B)
    float* h     = (float*)d_ws;                 // 6,400,000
    u32*   cnt   = (u32*)(h + (size_t)N_NODES * D);   // 100,000
    u32*   off   = cnt + N_NODES;                // 100,000
    u32*   cur   = off + N_NODES;                // 100,000
    u32*   bsum  = cur + N_NODES;                // 400 (NB=391, padded)
    u32*   bbase = bsum + 400;                   // 400
    int*   scol  = (int*)(bbase + 400);          // 1,600,000
    float* sval  = (float*)(scol + N_EDGES);     // 1,600,000
    // total ~39.2 MB

    hipLaunchKernelGGL(gemm_kernel, dim3(N_NODES / 16), dim3(256), 0, stream,
                       feat, kern, h);
    hipLaunchKernelGGL(zero_cnt, dim3(NB), dim3(256), 0, stream, cnt);
    hipLaunchKernelGGL(hist_kernel, dim3(N_EDGES / 256), dim3(256), 0, stream,
                       erow, cnt);
    hipLaunchKernelGGL(block_sums, dim3(NB), dim3(256), 0, stream, cnt, bsum);
    hipLaunchKernelGGL(scan_bsums, dim3(1), dim3(512), 0, stream, bsum, bbase);
    hipLaunchKernelGGL(scan_final, dim3(NB), dim3(256), 0, stream, cnt, bbase,
                       off, cur);
    hipLaunchKernelGGL(scatter_kernel, dim3(N_EDGES / 256), dim3(256), 0, stream,
                       erow, ecol, eval, cur, scol, sval);
    hipLaunchKernelGGL(agg_kernel, dim3(N_NODES / 4), dim3(256), 0, stream,
                       off, cnt, scol, sval, h, skip, bias, out);
}

// Round 3
// 288.736 us; speedup vs baseline: 5.0824x; 1.3103x over previous
//
#include <hip/hip_runtime.h>
#include <math.h>

#define N_NODES 100000
#define N_EDGES 1600000
#define D 64
#define NB 391          // ceil(N_NODES/256)

typedef unsigned int u32;

// ---------------------------------------------------------------------------
// K1: h = feat @ kern  (fp32 vector GEMM, K=64, D_OUT=64)
// ---------------------------------------------------------------------------
__global__ __launch_bounds__(256) void gemm_kernel(
    const float* __restrict__ feat, const float* __restrict__ kern,
    float* __restrict__ h)
{
    __shared__ float ks[64 * 64];
    __shared__ float fs[16 * 64];

    const int t = threadIdx.x;
    const int row0 = blockIdx.x * 16;

    {
        const float4* k4 = (const float4*)kern;
        float4* ks4 = (float4*)ks;
        #pragma unroll
        for (int i = 0; i < 4; i++) ks4[t + 256 * i] = k4[t + 256 * i];
    }
    {
        const float4* f4 = (const float4*)(feat + (size_t)row0 * D);
        ((float4*)fs)[t] = f4[t];
    }
    __syncthreads();

    const int r  = t >> 4;
    const int cg = t & 15;

    float4 acc = make_float4(0.f, 0.f, 0.f, 0.f);
    #pragma unroll
    for (int k4 = 0; k4 < 16; k4++) {
        float4 f  = ((const float4*)(fs + r * D))[k4];
        float4 k0 = ((const float4*)(ks + (4 * k4 + 0) * D))[cg];
        float4 k1 = ((const float4*)(ks + (4 * k4 + 1) * D))[cg];
        float4 k2 = ((const float4*)(ks + (4 * k4 + 2) * D))[cg];
        float4 k3 = ((const float4*)(ks + (4 * k4 + 3) * D))[cg];
        acc.x += f.x * k0.x + f.y * k1.x + f.z * k2.x + f.w * k3.x;
        acc.y += f.x * k0.y + f.y * k1.y + f.z * k2.y + f.w * k3.y;
        acc.z += f.x * k0.z + f.y * k1.z + f.z * k2.z + f.w * k3.z;
        acc.w += f.x * k0.w + f.y * k1.w + f.z * k2.w + f.w * k3.w;
    }
    ((float4*)(h + (size_t)(row0 + r) * D))[cg] = acc;
}

// ---------------------------------------------------------------------------
// CSR build
// ---------------------------------------------------------------------------
__global__ void zero_cnt(u32* __restrict__ cnt)
{
    int i = blockIdx.x * 256 + threadIdx.x;
    if (i < N_NODES) cnt[i] = 0u;
}

// histogram + per-edge rank (fused): rank[i] = old count of row
__global__ void hist_rank_kernel(const int* __restrict__ erow,
                                 u32* __restrict__ cnt, u32* __restrict__ rank)
{
    int i = blockIdx.x * 256 + threadIdx.x;   // exactly N_EDGES threads
    rank[i] = atomicAdd(&cnt[erow[i]], 1u);
}

__global__ void block_sums(const u32* __restrict__ cnt, u32* __restrict__ bsum)
{
    __shared__ u32 s[256];
    int t = threadIdx.x;
    int i = blockIdx.x * 256 + t;
    s[t] = (i < N_NODES) ? cnt[i] : 0u;
    __syncthreads();
    for (int d = 128; d > 0; d >>= 1) {
        if (t < d) s[t] += s[t + d];
        __syncthreads();
    }
    if (t == 0) bsum[blockIdx.x] = s[0];
}

__global__ void scan_bsums(const u32* __restrict__ bsum, u32* __restrict__ bbase)
{
    __shared__ u32 s[512];
    int t = threadIdx.x;
    u32 v = (t < NB) ? bsum[t] : 0u;
    s[t] = v;
    __syncthreads();
    for (int d = 1; d < 512; d <<= 1) {
        u32 a = (t >= d) ? s[t - d] : 0u;
        __syncthreads();
        s[t] += a;
        __syncthreads();
    }
    if (t < NB) bbase[t] = s[t] - v;   // exclusive
}

__global__ void scan_final(const u32* __restrict__ cnt, const u32* __restrict__ bbase,
                           u32* __restrict__ off)
{
    __shared__ u32 s[256];
    int t = threadIdx.x;
    int i = blockIdx.x * 256 + t;
    u32 v = (i < N_NODES) ? cnt[i] : 0u;
    s[t] = v;
    __syncthreads();
    for (int d = 1; d < 256; d <<= 1) {
        u32 a = (t >= d) ? s[t - d] : 0u;
        __syncthreads();
        s[t] += a;
        __syncthreads();
    }
    if (i < N_NODES) off[i] = bbase[blockIdx.x] + s[t] - v;   // exclusive
}

// atomic-free placement: p = off[row] + rank, single packed 8B store
__global__ void place_kernel(const int* __restrict__ erow, const int* __restrict__ ecol,
                             const float* __restrict__ eval, const u32* __restrict__ off,
                             const u32* __restrict__ rank, int2* __restrict__ sedge)
{
    int i = blockIdx.x * 256 + threadIdx.x;   // exactly N_EDGES threads
    int r = erow[i];
    u32 p = off[r] + rank[i];
    sedge[p] = make_int2(ecol[i], __float_as_int(eval[i]));
}

// ---------------------------------------------------------------------------
// Aggregation: one wave per row, lane = output dim; fused skip/bias + SELU
// ---------------------------------------------------------------------------
__global__ __launch_bounds__(256) void agg_kernel(
    const u32* __restrict__ off, const u32* __restrict__ cnt,
    const int2* __restrict__ sedge,
    const float* __restrict__ h, const float* __restrict__ skip,
    const float* __restrict__ bias, float* __restrict__ out)
{
    const int row  = blockIdx.x * 4 + (threadIdx.x >> 6);   // exactly N_NODES waves
    const int lane = threadIdx.x & 63;

    u32 j   = off[row];
    u32 end = j + cnt[row];
    float acc = 0.f;

    for (; j + 4 <= end; j += 4) {
        int2 e0 = sedge[j],     e1 = sedge[j + 1];
        int2 e2 = sedge[j + 2], e3 = sedge[j + 3];
        float h0 = h[(size_t)e0.x * D + lane];
        float h1 = h[(size_t)e1.x * D + lane];
        float h2 = h[(size_t)e2.x * D + lane];
        float h3 = h[(size_t)e3.x * D + lane];
        acc += __int_as_float(e0.y) * h0;
        acc += __int_as_float(e1.y) * h1;
        acc += __int_as_float(e2.y) * h2;
        acc += __int_as_float(e3.y) * h3;
    }
    for (; j < end; ++j) {
        int2 e = sedge[j];
        acc += __int_as_float(e.y) * h[(size_t)e.x * D + lane];
    }

    float x = h[(size_t)row * D + lane] * skip[lane] + bias[lane] + acc;
    const float scale = 1.0507009873554805f;
    const float alpha = 1.6732632423543772f;
    out[(size_t)row * D + lane] = x > 0.f ? scale * x
                                          : scale * alpha * (expf(x) - 1.f);
}

extern "C" void kernel_launch(void* const* d_in, const int* in_sizes, int n_in,
                              void* d_out, int out_size, void* d_ws, size_t ws_size,
                              hipStream_t stream)
{
    const float* feat = (const float*)d_in[0];
    const float* kern = (const float*)d_in[1];
    const float* bias = (const float*)d_in[2];
    const float* skip = (const float*)d_in[3];
    const int*   erow = (const int*)d_in[4];
    const int*   ecol = (const int*)d_in[5];
    const float* eval = (const float*)d_in[6];
    float* out = (float*)d_out;

    // workspace layout (all 4/8 B elements)
    float* h     = (float*)d_ws;                        // 6,400,000 f
    u32*   cnt   = (u32*)(h + (size_t)N_NODES * D);     // 100,000
    u32*   off   = cnt + N_NODES;                       // 100,000
    u32*   bsum  = off + N_NODES;                       // 400
    u32*   bbase = bsum + 400;                          // 400
    u32*   rank  = bbase + 400;                         // 1,600,000
    int2*  sedge = (int2*)(rank + N_EDGES);             // 1,600,000 int2
    // total ~46 MB

    hipLaunchKernelGGL(gemm_kernel, dim3(N_NODES / 16), dim3(256), 0, stream,
                       feat, kern, h);
    hipLaunchKernelGGL(zero_cnt, dim3(NB), dim3(256), 0, stream, cnt);
    hipLaunchKernelGGL(hist_rank_kernel, dim3(N_EDGES / 256), dim3(256), 0, stream,
                       erow, cnt, rank);
    hipLaunchKernelGGL(block_sums, dim3(NB), dim3(256), 0, stream, cnt, bsum);
    hipLaunchKernelGGL(scan_bsums, dim3(1), dim3(512), 0, stream, bsum, bbase);
    hipLaunchKernelGGL(scan_final, dim3(NB), dim3(256), 0, stream, cnt, bbase, off);
    hipLaunchKernelGGL(place_kernel, dim3(N_EDGES / 256), dim3(256), 0, stream,
                       erow, ecol, eval, off, rank, sedge);
    hipLaunchKernelGGL(agg_kernel, dim3(N_NODES / 4), dim3(256), 0, stream,
                       off, cnt, sedge, h, skip, bias, out);
}

// Round 4
// 284.751 us; speedup vs baseline: 5.1535x; 1.0140x over previous
//
#include <hip/hip_runtime.h>
#include <math.h>

#define N_NODES 100000
#define N_EDGES 1600000
#define D 64
#define NB 391          // ceil(N_NODES/256)

typedef unsigned int u32;

// ---------------------------------------------------------------------------
// K1: h = feat @ kern  (fp32 vector GEMM, K=64, D_OUT=64)
// ---------------------------------------------------------------------------
__global__ __launch_bounds__(256) void gemm_kernel(
    const float* __restrict__ feat, const float* __restrict__ kern,
    float* __restrict__ h)
{
    __shared__ float ks[64 * 64];
    __shared__ float fs[16 * 64];

    const int t = threadIdx.x;
    const int row0 = blockIdx.x * 16;

    {
        const float4* k4 = (const float4*)kern;
        float4* ks4 = (float4*)ks;
        #pragma unroll
        for (int i = 0; i < 4; i++) ks4[t + 256 * i] = k4[t + 256 * i];
    }
    {
        const float4* f4 = (const float4*)(feat + (size_t)row0 * D);
        ((float4*)fs)[t] = f4[t];
    }
    __syncthreads();

    const int r  = t >> 4;
    const int cg = t & 15;

    float4 acc = make_float4(0.f, 0.f, 0.f, 0.f);
    #pragma unroll
    for (int k4 = 0; k4 < 16; k4++) {
        float4 f  = ((const float4*)(fs + r * D))[k4];
        float4 k0 = ((const float4*)(ks + (4 * k4 + 0) * D))[cg];
        float4 k1 = ((const float4*)(ks + (4 * k4 + 1) * D))[cg];
        float4 k2 = ((const float4*)(ks + (4 * k4 + 2) * D))[cg];
        float4 k3 = ((const float4*)(ks + (4 * k4 + 3) * D))[cg];
        acc.x += f.x * k0.x + f.y * k1.x + f.z * k2.x + f.w * k3.x;
        acc.y += f.x * k0.y + f.y * k1.y + f.z * k2.y + f.w * k3.y;
        acc.z += f.x * k0.z + f.y * k1.z + f.z * k2.z + f.w * k3.z;
        acc.w += f.x * k0.w + f.y * k1.w + f.z * k2.w + f.w * k3.w;
    }
    ((float4*)(h + (size_t)(row0 + r) * D))[cg] = acc;
}

// ---------------------------------------------------------------------------
// CSR build
// ---------------------------------------------------------------------------
__global__ void zero_cnt(u32* __restrict__ cnt)
{
    int i = blockIdx.x * 256 + threadIdx.x;
    if (i < N_NODES) cnt[i] = 0u;
}

// histogram + per-edge rank (fused): rank[i] = old count of row
__global__ void hist_rank_kernel(const int* __restrict__ erow,
                                 u32* __restrict__ cnt, u32* __restrict__ rank)
{
    int i = blockIdx.x * 256 + threadIdx.x;   // exactly N_EDGES threads
    rank[i] = atomicAdd(&cnt[erow[i]], 1u);
}

__global__ void block_sums(const u32* __restrict__ cnt, u32* __restrict__ bsum)
{
    __shared__ u32 s[256];
    int t = threadIdx.x;
    int i = blockIdx.x * 256 + t;
    s[t] = (i < N_NODES) ? cnt[i] : 0u;
    __syncthreads();
    for (int d = 128; d > 0; d >>= 1) {
        if (t < d) s[t] += s[t + d];
        __syncthreads();
    }
    if (t == 0) bsum[blockIdx.x] = s[0];
}

__global__ void scan_bsums(const u32* __restrict__ bsum, u32* __restrict__ bbase)
{
    __shared__ u32 s[512];
    int t = threadIdx.x;
    u32 v = (t < NB) ? bsum[t] : 0u;
    s[t] = v;
    __syncthreads();
    for (int d = 1; d < 512; d <<= 1) {
        u32 a = (t >= d) ? s[t - d] : 0u;
        __syncthreads();
        s[t] += a;
        __syncthreads();
    }
    if (t < NB) bbase[t] = s[t] - v;   // exclusive
}

__global__ void scan_final(const u32* __restrict__ cnt, const u32* __restrict__ bbase,
                           u32* __restrict__ off)
{
    __shared__ u32 s[256];
    int t = threadIdx.x;
    int i = blockIdx.x * 256 + t;
    u32 v = (i < N_NODES) ? cnt[i] : 0u;
    s[t] = v;
    __syncthreads();
    for (int d = 1; d < 256; d <<= 1) {
        u32 a = (t >= d) ? s[t - d] : 0u;
        __syncthreads();
        s[t] += a;
        __syncthreads();
    }
    if (i < N_NODES) off[i] = bbase[blockIdx.x] + s[t] - v;   // exclusive
}

// atomic-free placement: p = off[row] + rank, single packed 8B store
__global__ void place_kernel(const int* __restrict__ erow, const int* __restrict__ ecol,
                             const float* __restrict__ eval, const u32* __restrict__ off,
                             const u32* __restrict__ rank, int2* __restrict__ sedge)
{
    int i = blockIdx.x * 256 + threadIdx.x;   // exactly N_EDGES threads
    int r = erow[i];
    u32 p = off[r] + rank[i];
    sedge[p] = make_int2(ecol[i], __float_as_int(eval[i]));
}

// ---------------------------------------------------------------------------
// Aggregation: one wave per row. Quarter-wave q handles edge j+q; each lane
// loads float4 of dims (lane&15)*4 -> one dwordx4 serves 4 edges (1 KB).
// Cross-quarter shuffle reduction, fused skip/bias + SELU epilogue.
// ---------------------------------------------------------------------------
__global__ __launch_bounds__(256) void agg_kernel(
    const u32* __restrict__ off, const u32* __restrict__ cnt,
    const int2* __restrict__ sedge,
    const float* __restrict__ h, const float* __restrict__ skip,
    const float* __restrict__ bias, float* __restrict__ out)
{
    const int row  = blockIdx.x * 4 + (threadIdx.x >> 6);   // exactly N_NODES waves
    const int lane = threadIdx.x & 63;
    const int sub  = lane >> 4;    // quarter-wave: which edge in group of 4
    const int dg   = lane & 15;    // dim group: 4 consecutive dims

    const u32 beg = off[row];
    const u32 end = beg + cnt[row];

    float4 acc = make_float4(0.f, 0.f, 0.f, 0.f);

    for (u32 j = beg; j < end; j += 8) {
        u32 ja = j + sub;
        u32 jb = j + 4 + sub;
        int2 ea = (ja < end) ? sedge[ja] : make_int2(0, 0);
        int2 eb = (jb < end) ? sedge[jb] : make_int2(0, 0);
        float va = __int_as_float(ea.y);
        float vb = __int_as_float(eb.y);
        float4 ha = ((const float4*)(h + (size_t)ea.x * D))[dg];
        float4 hb = ((const float4*)(h + (size_t)eb.x * D))[dg];
        acc.x += va * ha.x; acc.y += va * ha.y;
        acc.z += va * ha.z; acc.w += va * ha.w;
        acc.x += vb * hb.x; acc.y += vb * hb.y;
        acc.z += vb * hb.z; acc.w += vb * hb.w;
    }

    // reduce across the 4 quarter-waves (lanes differing in bits 4,5)
    acc.x += __shfl_xor(acc.x, 16); acc.y += __shfl_xor(acc.y, 16);
    acc.z += __shfl_xor(acc.z, 16); acc.w += __shfl_xor(acc.w, 16);
    acc.x += __shfl_xor(acc.x, 32); acc.y += __shfl_xor(acc.y, 32);
    acc.z += __shfl_xor(acc.z, 32); acc.w += __shfl_xor(acc.w, 32);

    if (sub == 0) {
        float4 hr = ((const float4*)(h + (size_t)row * D))[dg];
        float4 sk = ((const float4*)skip)[dg];
        float4 bi = ((const float4*)bias)[dg];
        float4 x;
        x.x = hr.x * sk.x + bi.x + acc.x;
        x.y = hr.y * sk.y + bi.y + acc.y;
        x.z = hr.z * sk.z + bi.z + acc.z;
        x.w = hr.w * sk.w + bi.w + acc.w;
        const float scale = 1.0507009873554805f;
        const float alpha = 1.6732632423543772f;
        x.x = x.x > 0.f ? scale * x.x : scale * alpha * (expf(x.x) - 1.f);
        x.y = x.y > 0.f ? scale * x.y : scale * alpha * (expf(x.y) - 1.f);
        x.z = x.z > 0.f ? scale * x.z : scale * alpha * (expf(x.z) - 1.f);
        x.w = x.w > 0.f ? scale * x.w : scale * alpha * (expf(x.w) - 1.f);
        ((float4*)(out + (size_t)row * D))[dg] = x;
    }
}

extern "C" void kernel_launch(void* const* d_in, const int* in_sizes, int n_in,
                              void* d_out, int out_size, void* d_ws, size_t ws_size,
                              hipStream_t stream)
{
    const float* feat = (const float*)d_in[0];
    const float* kern = (const float*)d_in[1];
    const float* bias = (const float*)d_in[2];
    const float* skip = (const float*)d_in[3];
    const int*   erow = (const int*)d_in[4];
    const int*   ecol = (const int*)d_in[5];
    const float* eval = (const float*)d_in[6];
    float* out = (float*)d_out;

    // workspace layout (all 4/8 B elements)
    float* h     = (float*)d_ws;                        // 6,400,000 f
    u32*   cnt   = (u32*)(h + (size_t)N_NODES * D);     // 100,000
    u32*   off   = cnt + N_NODES;                       // 100,000
    u32*   bsum  = off + N_NODES;                       // 400
    u32*   bbase = bsum + 400;                          // 400
    u32*   rank  = bbase + 400;                         // 1,600,000
    int2*  sedge = (int2*)(rank + N_EDGES);             // 1,600,000 int2
    // total ~46 MB

    hipLaunchKernelGGL(gemm_kernel, dim3(N_NODES / 16), dim3(256), 0, stream,
                       feat, kern, h);
    hipLaunchKernelGGL(zero_cnt, dim3(NB), dim3(256), 0, stream, cnt);
    hipLaunchKernelGGL(hist_rank_kernel, dim3(N_EDGES / 256), dim3(256), 0, stream,
                       erow, cnt, rank);
    hipLaunchKernelGGL(block_sums, dim3(NB), dim3(256), 0, stream, cnt, bsum);
    hipLaunchKernelGGL(scan_bsums, dim3(1), dim3(512), 0, stream, bsum, bbase);
    hipLaunchKernelGGL(scan_final, dim3(NB), dim3(256), 0, stream, cnt, bbase, off);
    hipLaunchKernelGGL(place_kernel, dim3(N_EDGES / 256), dim3(256), 0, stream,
                       erow, ecol, eval, off, rank, sedge);
    hipLaunchKernelGGL(agg_kernel, dim3(N_NODES / 4), dim3(256), 0, stream,
                       off, cnt, sedge, h, skip, bias, out);
}